// Round 19
// baseline (33.963 us; speedup 1.0000x reference)
//
#include <hip/hip_runtime.h>

typedef float v2f __attribute__((ext_vector_type(2)));

// Canonical wave64 inclusive prefix-sum (AMD GCN scan sequence).
__device__ __forceinline__ float scan64(float d) {
    d += __int_as_float(__builtin_amdgcn_update_dpp(0, __float_as_int(d), 0x111, 0xF, 0xF, true));
    d += __int_as_float(__builtin_amdgcn_update_dpp(0, __float_as_int(d), 0x112, 0xF, 0xF, true));
    d += __int_as_float(__builtin_amdgcn_update_dpp(0, __float_as_int(d), 0x114, 0xF, 0xF, true));
    d += __int_as_float(__builtin_amdgcn_update_dpp(0, __float_as_int(d), 0x118, 0xF, 0xF, true));
    d += __int_as_float(__builtin_amdgcn_update_dpp(0, __float_as_int(d), 0x142, 0xA, 0xF, true));
    d += __int_as_float(__builtin_amdgcn_update_dpp(0, __float_as_int(d), 0x143, 0xC, 0xF, true));
    return d;
}

// wave-uniform broadcast of lane 63 (no LDS round-trip)
__device__ __forceinline__ float rdl63(float v) {
    return __int_as_float(__builtin_amdgcn_readlane(__float_as_int(v), 63));
}

// 256-step blocks, 4 steps/lane, ONE MLP/lane/block, J collapsed to 6
// scalars (round 18, 33.8us). This round: t-prefetch DEPTH 2 (t for blocks
// g and g+1 resident; g+2 issued each iteration) so the ~600-900cy load
// latency is covered by ~2 block-chains and the carry path's tb-next is
// always already-resident. dm-walk restructured to prefix form (depth 4).
__global__ __launch_bounds__(64, 4) void ode_wf256x4d2(
    const float* __restrict__ thr,   // B x (N+1)
    const float* __restrict__ DOD,   // B
    const float* __restrict__ Vav,   // B
    const float* __restrict__ C0,    // B
    const float* __restrict__ R0,    // B
    const float* __restrict__ W1,    // 10 x 5
    const float* __restrict__ b1,    // 10
    const float* __restrict__ W2,    // 5 x 10
    const float* __restrict__ b2,    // 5
    float* __restrict__ out,         // B x (N+1) x 2
    int B, int N)
{
    const int j   = threadIdx.x & 63;
    const int row = blockIdx.x;         // 1 row per wave
    if (row >= B) return;

    // tanh(p) = 1 - 2/(1+e^{2p}); fold 2*log2(e) into layer-1, "+1" into
    // c3/c4, "-2" into wa/wb. Hidden units packed (h, h+5) -> v_pk_* fp32.
    const float k2  = 2.0f * 1.4426950408889634f;
    const float ln2 = 0.6931471805599453f;
    const float dod = DOD[row], vav = Vav[row];

    v2f bw[5], w0k[5], w3k[5], w4k[5], wa[5], wb[5];
    float c3 = b2[3], c4 = b2[4];
#pragma unroll
    for (int i = 0; i < 5; ++i) {
#pragma unroll
        for (int p = 0; p < 2; ++p) {
            int h = i + 5 * p;
            float a0 = W1[h * 5 + 0];
            float a1 = W1[h * 5 + 1];
            float a2 = W1[h * 5 + 2];
            float a3 = W1[h * 5 + 3];
            float a4 = W1[h * 5 + 4];
            bw[i][p]  = k2 * (b1[h] + a1 * dod + a2 * vav);
            w0k[i][p] = k2 * a0;
            w3k[i][p] = k2 * a3;
            w4k[i][p] = k2 * a4;
            float v3 = W2[30 + h];
            float v4 = W2[40 + h];
            c3 += v3; c4 += v4;
            wa[i][p] = -2.0f * v3;
            wb[i][p] = -2.0f * v4;
        }
    }

    float Y3 = C0[row], Y4 = R0[row];            // exact state entering block
    const float* trp = thr + (size_t)row * (size_t)(N + 1);
    float2* orow = (float2*)(out + (size_t)row * (size_t)(N + 1) * 2);
    if (j == 0) orow[0] = make_float2(Y3, Y4);

    // t buffers: tc = block g (resident), tn = block g+1 (resident)
    float tc[5], tn[5], tbc, tbn;
#pragma unroll
    for (int k = 0; k < 5; ++k) tc[k] = trp[min(4 * j + k, N)];
    tbc = trp[0];
#pragma unroll
    for (int k = 0; k < 5; ++k) tn[k] = trp[min(256 + 4 * j + k, N)];
    tbn = trp[min(256, N)];

    // bootstrap slope F(Y, tb)
    float F3p, F4p;
    {
        v2f Fa = {c3, 0.f}, Fb = {c4, 0.f};
#pragma unroll
        for (int i = 0; i < 5; ++i) {
            v2f x = w3k[i] * Y3 + (w4k[i] * Y4 + (w0k[i] * tbc + bw[i]));
            v2f e; e.x = __builtin_amdgcn_exp2f(x.x); e.y = __builtin_amdgcn_exp2f(x.y);
            v2f A = e + 1.0f;
            v2f s; s.x = __builtin_amdgcn_rcpf(A.x); s.y = __builtin_amdgcn_rcpf(A.y);
            Fa += wa[i] * s;
            Fb += wb[i] * s;
        }
        F3p = Fa.x + Fa.y; F4p = Fb.x + Fb.y;
    }
    float dF3 = 0.f, dF4 = 0.f;

    const int nblk = (N + 255) >> 8;

    for (int g = 0; g < nblk; ++g) {
        const int base = g << 8;

        // issue depth-2 prefetch (block g+2) FIRST; consumed 2 iterations on
        const int pf = base + 512;
        float tf[5], tbf;
#pragma unroll
        for (int k = 0; k < 5; ++k) tf[k] = trp[min(pf + 4 * j + k, N)];
        tbf = trp[min(pf, N)];

        const float h0 = tc[1] - tc[0];          // 0 on clamped lanes
        const float h1 = tc[2] - tc[1];
        const float h2 = tc[3] - tc[2];
        const float h3 = tc[4] - tc[3];

        // 2nd-order predictor at the 4 points
        float z3[4], z4[4];
#pragma unroll
        for (int k = 0; k < 4; ++k) {
            float dt = tc[k] - tbc;
            z3[k] = fmaf(dt, fmaf(0.5f * dt, dF3, F3p), Y3);
            z4[k] = fmaf(dt, fmaf(0.5f * dt, dF4, F4p), Y4);
        }

        // ---- ONE full MLP eval at (z[0], t0); keep s -> Jacobian weights ----
        v2f tq[5];
        float F30, F40;
        {
            v2f Fa = {c3, 0.f}, Fb = {c4, 0.f};
#pragma unroll
            for (int i = 0; i < 5; ++i) {
                v2f x = w3k[i] * z3[0] + (w4k[i] * z4[0] + (w0k[i] * tc[0] + bw[i]));
                v2f e; e.x = __builtin_amdgcn_exp2f(x.x);
                       e.y = __builtin_amdgcn_exp2f(x.y);
                v2f A = e + 1.0f;
                v2f s; s.x = __builtin_amdgcn_rcpf(A.x);
                       s.y = __builtin_amdgcn_rcpf(A.y);
                tq[i] = s;
                Fa += wa[i] * s;
                Fb += wb[i] * s;
            }
            F30 = Fa.x + Fa.y; F40 = Fb.x + Fb.y;
        }
#pragma unroll
        for (int i = 0; i < 5; ++i) tq[i] = tq[i] - tq[i] * tq[i];  // s(1-s)

        // ---- Jacobian collapsed to 6 per-lane scalars (pre-scaled ln2) ----
        float K3a, K4a, Kta, K3b, K4b, Ktb;
        {
            v2f a3 = {0.f,0.f}, a4 = {0.f,0.f}, at = {0.f,0.f};
            v2f b3 = {0.f,0.f}, b4 = {0.f,0.f}, bt = {0.f,0.f};
#pragma unroll
            for (int i = 0; i < 5; ++i) {
                v2f ma = wa[i] * tq[i];
                v2f mb = wb[i] * tq[i];
                a3 += ma * w3k[i]; a4 += ma * w4k[i]; at += ma * w0k[i];
                b3 += mb * w3k[i]; b4 += mb * w4k[i]; bt += mb * w0k[i];
            }
            K3a = ln2 * (a3.x + a3.y); K4a = ln2 * (a4.x + a4.y);
            Kta = ln2 * (at.x + at.y);
            K3b = ln2 * (b3.x + b3.y); K4b = ln2 * (b4.x + b4.y);
            Ktb = ln2 * (bt.x + bt.y);
        }

        // ---- slopes at points 1..3 via J (scalar form) ----
        float F3v[4], F4v[4];
        F3v[0] = F30; F4v[0] = F40;
#pragma unroll
        for (int k = 1; k < 4; ++k) {
            float D3 = z3[k] - z3[0];
            float D4 = z4[k] - z4[0];
            float Dt = tc[k] - tc[0];
            F3v[k] = F30 - fmaf(K3a, D3, fmaf(K4a, D4, Kta * Dt));
            F4v[k] = F40 - fmaf(K3b, D3, fmaf(K4b, D4, Ktb * Dt));
        }

        // ---- sweep 1: combined increment, one scan-pair over 256 steps ----
        float d3 = fmaf(h0, F3v[0], fmaf(h1, F3v[1], fmaf(h2, F3v[2], h3 * F3v[3])));
        float d4 = fmaf(h0, F4v[0], fmaf(h1, F4v[1], fmaf(h2, F4v[2], h3 * F4v[3])));
        float S3 = scan64(d3);
        float S4 = scan64(d4);

        // corrected states in prefix form (depth ~4, high ILP) -> dm
        float dm3, dm4;
        {
            float cb3 = Y3 + (S3 - d3), cb4 = Y4 + (S4 - d4);
            float a1 = h0 * F3v[0];
            float a2 = fmaf(h1, F3v[1], a1);
            float a3 = fmaf(h2, F3v[2], a2);
            float b1_ = h0 * F4v[0];
            float b2_ = fmaf(h1, F4v[1], b1_);
            float b3_ = fmaf(h2, F4v[2], b2_);
            float e0 = cb3 - z3[0];
            float e1 = (cb3 + a1) - z3[1];
            float e2 = (cb3 + a2) - z3[2];
            float e3 = (cb3 + a3) - z3[3];
            dm3 = fmaf(h0, e0, h1 * e1) + fmaf(h2, e2, h3 * e3);
            float f0 = cb4 - z4[0];
            float f1 = (cb4 + b1_) - z4[1];
            float f2 = (cb4 + b2_) - z4[2];
            float f3 = (cb4 + b3_) - z4[3];
            dm4 = fmaf(h0, f0, h1 * f1) + fmaf(h2, f2, h3 * f3);
        }

        // ---- sweep 2 fused through J (scalar), second scan-pair ----
        float d3p = d3 - fmaf(K3a, dm3, K4a * dm4);
        float d4p = d4 - fmaf(K3b, dm3, K4b * dm4);
        float S3p = scan64(d3p);
        float S4p = scan64(d4p);

        // ---- outputs: back-recovery from the step-(4j+3) state ----
        float o3 = Y3 + S3p, o4 = Y4 + S4p;
        const int p0 = base + 4 * j;
        if (p0 + 3 < N) orow[p0 + 4] = make_float2(o3, o4);
        float q3 = fmaf(-h3, F3v[3], o3), q4 = fmaf(-h3, F4v[3], o4);
        if (p0 + 2 < N) orow[p0 + 3] = make_float2(q3, q4);
        q3 = fmaf(-h2, F3v[2], q3); q4 = fmaf(-h2, F4v[2], q4);
        if (p0 + 1 < N) orow[p0 + 2] = make_float2(q3, q4);
        q3 = fmaf(-h1, F3v[1], q3); q4 = fmaf(-h1, F4v[1], q4);
        if (p0 < N)     orow[p0 + 1] = make_float2(q3, q4);

        // ---- carry via readlane; span uses RESIDENT tbn (no load wait) ----
        float F3n = rdl63(F3v[3]);
        float F4n = rdl63(F4v[3]);
        Y3 += rdl63(S3p);
        Y4 += rdl63(S4p);
        float span = tbn - tbc;
        float inv = (span > 0.f) ? __builtin_amdgcn_rcpf(span) : 0.f;
        dF3 = (F3n - F3p) * inv;
        dF4 = (F4n - F4p) * inv;
        F3p = F3n; F4p = F4n;

        // rotate t buffers: g+1 -> current, g+2 -> next
#pragma unroll
        for (int k = 0; k < 5; ++k) { tc[k] = tn[k]; tn[k] = tf[k]; }
        tbc = tbn; tbn = tbf;
    }
}

extern "C" void kernel_launch(void* const* d_in, const int* in_sizes, int n_in,
                              void* d_out, int out_size, void* d_ws, size_t ws_size,
                              hipStream_t stream) {
    const float* thr = (const float*)d_in[0];
    const float* DOD = (const float*)d_in[1];
    const float* Vav = (const float*)d_in[2];
    const float* C0  = (const float*)d_in[3];
    const float* R0  = (const float*)d_in[4];
    const float* W1  = (const float*)d_in[5];
    const float* b1  = (const float*)d_in[6];
    const float* W2  = (const float*)d_in[7];
    const float* b2  = (const float*)d_in[8];
    float* out = (float*)d_out;

    int B = in_sizes[1];             // DOD is (1,B)
    int N = in_sizes[0] / B - 1;     // throughput is (B, N+1)

    dim3 block(64);
    dim3 grid(B);                    // 1 row per 64-thread wave
    ode_wf256x4d2<<<grid, block, 0, stream>>>(thr, DOD, Vav, C0, R0,
                                              W1, b1, W2, b2, out, B, N);
}

// Round 20
// 29.979 us; speedup vs baseline: 1.1329x; 1.1329x over previous
//
#include <hip/hip_runtime.h>

typedef float v2f __attribute__((ext_vector_type(2)));

// Canonical wave64 inclusive prefix-sum (AMD GCN scan sequence).
__device__ __forceinline__ float scan64(float d) {
    d += __int_as_float(__builtin_amdgcn_update_dpp(0, __float_as_int(d), 0x111, 0xF, 0xF, true));
    d += __int_as_float(__builtin_amdgcn_update_dpp(0, __float_as_int(d), 0x112, 0xF, 0xF, true));
    d += __int_as_float(__builtin_amdgcn_update_dpp(0, __float_as_int(d), 0x114, 0xF, 0xF, true));
    d += __int_as_float(__builtin_amdgcn_update_dpp(0, __float_as_int(d), 0x118, 0xF, 0xF, true));
    d += __int_as_float(__builtin_amdgcn_update_dpp(0, __float_as_int(d), 0x142, 0xA, 0xF, true));
    d += __int_as_float(__builtin_amdgcn_update_dpp(0, __float_as_int(d), 0x143, 0xC, 0xF, true));
    return d;
}

// wave-uniform broadcast of lane 63 (no LDS round-trip)
__device__ __forceinline__ float rdl63(float v) {
    return __int_as_float(__builtin_amdgcn_readlane(__float_as_int(v), 63));
}

// Round 19 math, store path replaced: 4x scattered 8B stores -> 2x packed
// 16B-aligned float4 stores per lane. Row base is 16392B*row: even rows are
// 16B-aligned at index 4j (store states after steps p0-1..p0+2, first element
// = exclusive-corrected base), odd rows at index 4j+1 (store after p0..p0+3).
__global__ __launch_bounds__(64, 4) void ode_wf256x4st(
    const float* __restrict__ thr,   // B x (N+1)
    const float* __restrict__ DOD,   // B
    const float* __restrict__ Vav,   // B
    const float* __restrict__ C0,    // B
    const float* __restrict__ R0,    // B
    const float* __restrict__ W1,    // 10 x 5
    const float* __restrict__ b1,    // 10
    const float* __restrict__ W2,    // 5 x 10
    const float* __restrict__ b2,    // 5
    float* __restrict__ out,         // B x (N+1) x 2
    int B, int N)
{
    const int j   = threadIdx.x & 63;
    const int row = blockIdx.x;         // 1 row per wave
    if (row >= B) return;

    const float k2  = 2.0f * 1.4426950408889634f;
    const float ln2 = 0.6931471805599453f;
    const float dod = DOD[row], vav = Vav[row];

    v2f bw[5], w0k[5], w3k[5], w4k[5], wa[5], wb[5];
    float c3 = b2[3], c4 = b2[4];
#pragma unroll
    for (int i = 0; i < 5; ++i) {
#pragma unroll
        for (int p = 0; p < 2; ++p) {
            int h = i + 5 * p;
            float a0 = W1[h * 5 + 0];
            float a1 = W1[h * 5 + 1];
            float a2 = W1[h * 5 + 2];
            float a3 = W1[h * 5 + 3];
            float a4 = W1[h * 5 + 4];
            bw[i][p]  = k2 * (b1[h] + a1 * dod + a2 * vav);
            w0k[i][p] = k2 * a0;
            w3k[i][p] = k2 * a3;
            w4k[i][p] = k2 * a4;
            float v3 = W2[30 + h];
            float v4 = W2[40 + h];
            c3 += v3; c4 += v4;
            wa[i][p] = -2.0f * v3;
            wb[i][p] = -2.0f * v4;
        }
    }

    float Y3 = C0[row], Y4 = R0[row];            // exact state entering block
    const float* trp = thr + (size_t)row * (size_t)(N + 1);
    float2* orow = (float2*)(out + (size_t)row * (size_t)(N + 1) * 2);
    const bool alignA = ((row & 1) == 0);        // even rows: index 4j is 16B-aligned
    if (!alignA && j == 0) orow[0] = make_float2(Y3, Y4);
    // (alignA rows: block 0 / lane 0 writes index 0 = initial state automatically)

    // t buffers: tc = block g (resident), tn = block g+1 (resident)
    float tc[5], tn[5], tbc, tbn;
#pragma unroll
    for (int k = 0; k < 5; ++k) tc[k] = trp[min(4 * j + k, N)];
    tbc = trp[0];
#pragma unroll
    for (int k = 0; k < 5; ++k) tn[k] = trp[min(256 + 4 * j + k, N)];
    tbn = trp[min(256, N)];

    // bootstrap slope F(Y, tb)
    float F3p, F4p;
    {
        v2f Fa = {c3, 0.f}, Fb = {c4, 0.f};
#pragma unroll
        for (int i = 0; i < 5; ++i) {
            v2f x = w3k[i] * Y3 + (w4k[i] * Y4 + (w0k[i] * tbc + bw[i]));
            v2f e; e.x = __builtin_amdgcn_exp2f(x.x); e.y = __builtin_amdgcn_exp2f(x.y);
            v2f A = e + 1.0f;
            v2f s; s.x = __builtin_amdgcn_rcpf(A.x); s.y = __builtin_amdgcn_rcpf(A.y);
            Fa += wa[i] * s;
            Fb += wb[i] * s;
        }
        F3p = Fa.x + Fa.y; F4p = Fb.x + Fb.y;
    }
    float dF3 = 0.f, dF4 = 0.f;

    const int nblk = (N + 255) >> 8;
    const int nSt  = N >> 8;                     // blocks with base+256 <= N: packed stores

    for (int g = 0; g < nblk; ++g) {
        const int base = g << 8;

        // depth-2 prefetch (block g+2)
        const int pf = base + 512;
        float tf[5], tbf;
#pragma unroll
        for (int k = 0; k < 5; ++k) tf[k] = trp[min(pf + 4 * j + k, N)];
        tbf = trp[min(pf, N)];

        const float h0 = tc[1] - tc[0];          // 0 on clamped lanes
        const float h1 = tc[2] - tc[1];
        const float h2 = tc[3] - tc[2];
        const float h3 = tc[4] - tc[3];

        // 2nd-order predictor at the 4 points
        float z3[4], z4[4];
#pragma unroll
        for (int k = 0; k < 4; ++k) {
            float dt = tc[k] - tbc;
            z3[k] = fmaf(dt, fmaf(0.5f * dt, dF3, F3p), Y3);
            z4[k] = fmaf(dt, fmaf(0.5f * dt, dF4, F4p), Y4);
        }

        // ---- ONE full MLP eval at (z[0], t0); keep s -> Jacobian weights ----
        v2f tq[5];
        float F30, F40;
        {
            v2f Fa = {c3, 0.f}, Fb = {c4, 0.f};
#pragma unroll
            for (int i = 0; i < 5; ++i) {
                v2f x = w3k[i] * z3[0] + (w4k[i] * z4[0] + (w0k[i] * tc[0] + bw[i]));
                v2f e; e.x = __builtin_amdgcn_exp2f(x.x);
                       e.y = __builtin_amdgcn_exp2f(x.y);
                v2f A = e + 1.0f;
                v2f s; s.x = __builtin_amdgcn_rcpf(A.x);
                       s.y = __builtin_amdgcn_rcpf(A.y);
                tq[i] = s;
                Fa += wa[i] * s;
                Fb += wb[i] * s;
            }
            F30 = Fa.x + Fa.y; F40 = Fb.x + Fb.y;
        }
#pragma unroll
        for (int i = 0; i < 5; ++i) tq[i] = tq[i] - tq[i] * tq[i];  // s(1-s)

        // ---- Jacobian collapsed to 6 per-lane scalars (pre-scaled ln2) ----
        float K3a, K4a, Kta, K3b, K4b, Ktb;
        {
            v2f a3 = {0.f,0.f}, a4 = {0.f,0.f}, at = {0.f,0.f};
            v2f b3 = {0.f,0.f}, b4 = {0.f,0.f}, bt = {0.f,0.f};
#pragma unroll
            for (int i = 0; i < 5; ++i) {
                v2f ma = wa[i] * tq[i];
                v2f mb = wb[i] * tq[i];
                a3 += ma * w3k[i]; a4 += ma * w4k[i]; at += ma * w0k[i];
                b3 += mb * w3k[i]; b4 += mb * w4k[i]; bt += mb * w0k[i];
            }
            K3a = ln2 * (a3.x + a3.y); K4a = ln2 * (a4.x + a4.y);
            Kta = ln2 * (at.x + at.y);
            K3b = ln2 * (b3.x + b3.y); K4b = ln2 * (b4.x + b4.y);
            Ktb = ln2 * (bt.x + bt.y);
        }

        // ---- slopes at points 1..3 via J (scalar form) ----
        float F3v[4], F4v[4];
        F3v[0] = F30; F4v[0] = F40;
#pragma unroll
        for (int k = 1; k < 4; ++k) {
            float D3 = z3[k] - z3[0];
            float D4 = z4[k] - z4[0];
            float Dt = tc[k] - tc[0];
            F3v[k] = F30 - fmaf(K3a, D3, fmaf(K4a, D4, Kta * Dt));
            F4v[k] = F40 - fmaf(K3b, D3, fmaf(K4b, D4, Ktb * Dt));
        }

        // ---- sweep 1: combined increment, one scan-pair over 256 steps ----
        float d3 = fmaf(h0, F3v[0], fmaf(h1, F3v[1], fmaf(h2, F3v[2], h3 * F3v[3])));
        float d4 = fmaf(h0, F4v[0], fmaf(h1, F4v[1], fmaf(h2, F4v[2], h3 * F4v[3])));
        float S3 = scan64(d3);
        float S4 = scan64(d4);

        // corrected states in prefix form -> dm
        float dm3, dm4;
        {
            float cb3 = Y3 + (S3 - d3), cb4 = Y4 + (S4 - d4);
            float a1 = h0 * F3v[0];
            float a2 = fmaf(h1, F3v[1], a1);
            float a3 = fmaf(h2, F3v[2], a2);
            float b1_ = h0 * F4v[0];
            float b2_ = fmaf(h1, F4v[1], b1_);
            float b3_ = fmaf(h2, F4v[2], b2_);
            float e0 = cb3 - z3[0];
            float e1 = (cb3 + a1) - z3[1];
            float e2 = (cb3 + a2) - z3[2];
            float e3 = (cb3 + a3) - z3[3];
            dm3 = fmaf(h0, e0, h1 * e1) + fmaf(h2, e2, h3 * e3);
            float f0 = cb4 - z4[0];
            float f1 = (cb4 + b1_) - z4[1];
            float f2 = (cb4 + b2_) - z4[2];
            float f3 = (cb4 + b3_) - z4[3];
            dm4 = fmaf(h0, f0, h1 * f1) + fmaf(h2, f2, h3 * f3);
        }

        // ---- sweep 2 fused through J (scalar), second scan-pair ----
        float d3p = d3 - fmaf(K3a, dm3, K4a * dm4);
        float d4p = d4 - fmaf(K3b, dm3, K4b * dm4);
        float S3p = scan64(d3p);
        float S4p = scan64(d4p);

        // ---- outputs ----
        float o3 = Y3 + S3p, o4 = Y4 + S4p;               // after step p0+3
        float w23 = fmaf(-h3, F3v[3], o3), w24 = fmaf(-h3, F4v[3], o4); // p0+2
        float w13 = fmaf(-h2, F3v[2], w23), w14 = fmaf(-h2, F4v[2], w24); // p0+1
        float w03 = fmaf(-h1, F3v[1], w13), w04 = fmaf(-h1, F4v[1], w14); // p0
        const int p0 = base + 4 * j;
        if (g < nSt) {
            if (alignA) {
                // indices p0..p0+3 = states after steps p0-1..p0+2 (16B-aligned)
                float b3 = Y3 + (S3p - d3p), b4 = Y4 + (S4p - d4p); // after p0-1
                float4* dst = (float4*)(orow + p0);
                float4 v0 = {b3, b4, w03, w04};
                float4 v1 = {w13, w14, w23, w24};
                dst[0] = v0;
                dst[1] = v1;
                if (p0 + 4 == N) orow[N] = make_float2(o3, o4); // final element
            } else {
                // indices p0+1..p0+4 = states after steps p0..p0+3 (16B-aligned)
                float4* dst = (float4*)(orow + p0 + 1);
                float4 v0 = {w03, w04, w13, w14};
                float4 v1 = {w23, w24, o3, o4};
                dst[0] = v0;
                dst[1] = v1;
            }
        } else {
            // generic guarded tail (scalar float2 stores)
            if (alignA && j == 0) orow[base] = make_float2(Y3, Y4);
            if (p0 + 3 < N) orow[p0 + 4] = make_float2(o3, o4);
            if (p0 + 2 < N) orow[p0 + 3] = make_float2(w23, w24);
            if (p0 + 1 < N) orow[p0 + 2] = make_float2(w13, w14);
            if (p0 < N)     orow[p0 + 1] = make_float2(w03, w04);
        }

        // ---- carry via readlane; span uses resident tbn ----
        float F3n = rdl63(F3v[3]);
        float F4n = rdl63(F4v[3]);
        Y3 += rdl63(S3p);
        Y4 += rdl63(S4p);
        float span = tbn - tbc;
        float inv = (span > 0.f) ? __builtin_amdgcn_rcpf(span) : 0.f;
        dF3 = (F3n - F3p) * inv;
        dF4 = (F4n - F4p) * inv;
        F3p = F3n; F4p = F4n;

        // rotate t buffers
#pragma unroll
        for (int k = 0; k < 5; ++k) { tc[k] = tn[k]; tn[k] = tf[k]; }
        tbc = tbn; tbn = tbf;
    }
}

extern "C" void kernel_launch(void* const* d_in, const int* in_sizes, int n_in,
                              void* d_out, int out_size, void* d_ws, size_t ws_size,
                              hipStream_t stream) {
    const float* thr = (const float*)d_in[0];
    const float* DOD = (const float*)d_in[1];
    const float* Vav = (const float*)d_in[2];
    const float* C0  = (const float*)d_in[3];
    const float* R0  = (const float*)d_in[4];
    const float* W1  = (const float*)d_in[5];
    const float* b1  = (const float*)d_in[6];
    const float* W2  = (const float*)d_in[7];
    const float* b2  = (const float*)d_in[8];
    float* out = (float*)d_out;

    int B = in_sizes[1];             // DOD is (1,B)
    int N = in_sizes[0] / B - 1;     // throughput is (B, N+1)

    dim3 block(64);
    dim3 grid(B);                    // 1 row per 64-thread wave
    ode_wf256x4st<<<grid, block, 0, stream>>>(thr, DOD, Vav, C0, R0,
                                              W1, b1, W2, b2, out, B, N);
}